// Round 3
// baseline (79.203 us; speedup 1.0000x reference)
//
#include <hip/hip_runtime.h>
#include <math.h>

// CapsuleLinear routing, fp32 — priors eliminated; G=4 output capsules per block.
// logits_n = x_n . (W^T out_hat);  out = W . (sum_n p_n x_n)
// B=64, N=1152, I=8, O=64, L=16, 3 iters.
// Grid: 64 b x 16 o-groups = 1024 blocks. T=192 (3 waves), 6 rows/thread.

#define NCAPS 1152
#define ILEN  8
#define OCAPS 64
#define OLEN  16
#define T     192
#define NW    3
#define RPT   6        // 1152 / 192
#define G     4
#define NBLK_O (OCAPS / G)   // 16
#define NITER 3

// In-wave halving butterfly for 8-component vector reduce.
// Returns this lane's component sum; component index = bitrev3(lane&7).
#define BSTAGE(OFF, H)                                              \
    {                                                               \
        const bool up = (lane & (OFF)) != 0;                        \
        _Pragma("unroll")                                           \
        for (int j = 0; j < (H); ++j) {                             \
            float keep = up ? s[(H) + j] : s[j];                    \
            float send = up ? s[j] : s[(H) + j];                    \
            s[j] = keep + __shfl_xor(send, (OFF), 64);              \
        }                                                           \
    }

__device__ __forceinline__ float vec8_wave_reduce(float* s, int lane) {
    BSTAGE(1, 4)
    BSTAGE(2, 2)
    BSTAGE(4, 1)
    float s0 = s[0];
    s0 += __shfl_xor(s0, 8, 64);
    s0 += __shfl_xor(s0, 16, 64);
    s0 += __shfl_xor(s0, 32, 64);
    return s0;
}

__global__ __launch_bounds__(T, 3) void caps_kernel(const float* __restrict__ x,
                                                    const float* __restrict__ w,
                                                    float* __restrict__ dout,
                                                    int probs_base) {
    const int tid  = threadIdx.x;
    const int lane = tid & 63;
    const int wid  = tid >> 6;
    const int og = blockIdx.x & (NBLK_O - 1);
    const int b  = blockIdx.x >> 4;
    const int o0 = og * G;

    __shared__ __align__(16) float ws[G][OLEN * ILEN];   // 2 KB: W for 4 capsules
    __shared__ float red[NW][G][ILEN];
    __shared__ float redz[NW][G];
    __shared__ float ylds[G][ILEN];                      // y_g = W_g^T out_hat_g

    // stage W (512 floats)
    {
        const float* wsrc = w + (size_t)o0 * (OLEN * ILEN);
        float* wdst = &ws[0][0];
        #pragma unroll
        for (int j = 0; j < 3; ++j) {
            const int idx = tid + j * T;
            if (idx < G * OLEN * ILEN) wdst[idx] = wsrc[idx];
        }
    }

    // x rows -> registers
    const float* xb = x + (size_t)b * (NCAPS * ILEN);
    float xr[RPT][ILEN];
    #pragma unroll
    for (int k = 0; k < RPT; ++k) {
        const float4* q = (const float4*)(xb + (size_t)(tid + k * T) * ILEN);
        float4 a = q[0], c = q[1];
        xr[k][0] = a.x; xr[k][1] = a.y; xr[k][2] = a.z; xr[k][3] = a.w;
        xr[k][4] = c.x; xr[k][5] = c.y; xr[k][6] = c.z; xr[k][7] = c.w;
    }

    #pragma unroll
    for (int it = 0; it <= NITER; ++it) {
        float e[G][RPT];   // only live for it>0
        if (it == 0) {
            // initial centroid: uniform weights; s identical for all g
            float s[ILEN];
            #pragma unroll
            for (int i = 0; i < ILEN; ++i) {
                float acc = xr[0][i];
                #pragma unroll
                for (int k = 1; k < RPT; ++k) acc += xr[k][i];
                s[i] = acc;
            }
            const float s0 = vec8_wave_reduce(s, lane);
            if (lane < 8) {
                const int c = ((lane & 1) << 2) | (lane & 2) | ((lane & 4) >> 2);
                #pragma unroll
                for (int g = 0; g < G; ++g) red[wid][g][c] = s0;
            }
            if (lane == 0) {
                #pragma unroll
                for (int g = 0; g < G; ++g) redz[wid][g] = (float)NCAPS / (float)NW;
            }
        } else {
            #pragma unroll
            for (int g = 0; g < G; ++g) {
                float yv[ILEN];
                #pragma unroll
                for (int i = 0; i < ILEN; ++i) yv[i] = ylds[g][i];
                #pragma unroll
                for (int k = 0; k < RPT; ++k) {
                    float lg = xr[k][0] * yv[0];
                    #pragma unroll
                    for (int i = 1; i < ILEN; ++i) lg = fmaf(xr[k][i], yv[i], lg);
                    e[g][k] = __expf(lg);   // |lg| small; max-subtraction unneeded
                }
            }
            float s0g[G], zg[G];
            #pragma unroll
            for (int g = 0; g < G; ++g) {
                float s[ILEN];
                #pragma unroll
                for (int i = 0; i < ILEN; ++i) {
                    float acc = e[g][0] * xr[0][i];
                    #pragma unroll
                    for (int k = 1; k < RPT; ++k) acc = fmaf(e[g][k], xr[k][i], acc);
                    s[i] = acc;
                }
                float z = e[g][0];
                #pragma unroll
                for (int k = 1; k < RPT; ++k) z += e[g][k];
                s0g[g] = vec8_wave_reduce(s, lane);
                #pragma unroll
                for (int off = 1; off < 64; off <<= 1) z += __shfl_xor(z, off, 64);
                zg[g] = z;
            }
            if (lane < 8) {
                const int c = ((lane & 1) << 2) | (lane & 2) | ((lane & 4) >> 2);
                #pragma unroll
                for (int g = 0; g < G; ++g) red[wid][g][c] = s0g[g];
            }
            if (lane == 0) {
                #pragma unroll
                for (int g = 0; g < G; ++g) redz[wid][g] = zg[g];
            }
        }
        __syncthreads();

        if (it < NITER) {
            // waves 0,1: each handles 2 g's (32 lanes per g)
            if (wid < 2) {
                const int ge  = wid * 2 + (lane >> 5);
                const int sub = lane & 31;
                const int l   = sub & 15;
                float sb[ILEN];
                #pragma unroll
                for (int i = 0; i < ILEN; ++i)
                    sb[i] = red[0][ge][i] + red[1][ge][i] + red[2][ge][i];
                const float zinv = 1.0f / (redz[0][ge] + redz[1][ge] + redz[2][ge]);
                const float4 w0 = *(const float4*)&ws[ge][l * ILEN];
                const float4 w1 = *(const float4*)&ws[ge][l * ILEN + 4];
                float outl = w0.x * sb[0];
                outl = fmaf(w0.y, sb[1], outl);
                outl = fmaf(w0.z, sb[2], outl);
                outl = fmaf(w0.w, sb[3], outl);
                outl = fmaf(w1.x, sb[4], outl);
                outl = fmaf(w1.y, sb[5], outl);
                outl = fmaf(w1.z, sb[6], outl);
                outl = fmaf(w1.w, sb[7], outl);
                outl *= zinv;
                float n2 = outl * outl;
                n2 += __shfl_xor(n2, 1, 64);
                n2 += __shfl_xor(n2, 2, 64);
                n2 += __shfl_xor(n2, 4, 64);
                n2 += __shfl_xor(n2, 8, 64);
                const float inv = 1.0f / fmaxf(sqrtf(n2), 1e-12f);
                float ob[OLEN];
                const int gb = lane & 48;   // base lane of this 16-group
                #pragma unroll
                for (int l2 = 0; l2 < OLEN; ++l2) ob[l2] = __shfl(outl, gb + l2, 64);
                const int i8 = sub & 7;
                float yv = ws[ge][i8] * ob[0];
                #pragma unroll
                for (int l2 = 1; l2 < OLEN; ++l2)
                    yv = fmaf(ws[ge][l2 * ILEN + i8], ob[l2], yv);
                if (sub < 8) ylds[ge][i8] = yv * inv;
            }
            __syncthreads();
        } else {
            // final: write out (waves 0,1) and probs (all threads)
            if (wid < 2) {
                const int ge  = wid * 2 + (lane >> 5);
                const int sub = lane & 31;
                const int l   = sub & 15;
                float sb[ILEN];
                #pragma unroll
                for (int i = 0; i < ILEN; ++i)
                    sb[i] = red[0][ge][i] + red[1][ge][i] + red[2][ge][i];
                const float zinv = 1.0f / (redz[0][ge] + redz[1][ge] + redz[2][ge]);
                const float4 w0 = *(const float4*)&ws[ge][l * ILEN];
                const float4 w1 = *(const float4*)&ws[ge][l * ILEN + 4];
                float outl = w0.x * sb[0];
                outl = fmaf(w0.y, sb[1], outl);
                outl = fmaf(w0.z, sb[2], outl);
                outl = fmaf(w0.w, sb[3], outl);
                outl = fmaf(w1.x, sb[4], outl);
                outl = fmaf(w1.y, sb[5], outl);
                outl = fmaf(w1.z, sb[6], outl);
                outl = fmaf(w1.w, sb[7], outl);
                outl *= zinv;
                if (sub < 16)
                    dout[((size_t)(b * OCAPS + o0 + ge)) * OLEN + l] = outl;
            }
            float pinv[G];
            #pragma unroll
            for (int g = 0; g < G; ++g)
                pinv[g] = 1.0f / (redz[0][g] + redz[1][g] + redz[2][g]);
            #pragma unroll
            for (int g = 0; g < G; ++g) {
                float* pp = dout + (size_t)probs_base
                                 + (size_t)(b * OCAPS + o0 + g) * NCAPS;
                #pragma unroll
                for (int k = 0; k < RPT; ++k) pp[tid + k * T] = e[g][k] * pinv[g];
            }
        }
    }
}

extern "C" void kernel_launch(void* const* d_in, const int* in_sizes, int n_in,
                              void* d_out, int out_size, void* d_ws, size_t ws_size,
                              hipStream_t stream) {
    const float* x = (const float*)d_in[0];
    const float* w = (const float*)d_in[1];
    float* out = (float*)d_out;
    const int Bv = in_sizes[0] / (NCAPS * ILEN);   // 64
    const int nblocks = Bv * NBLK_O;               // 1024
    const int probs_base = Bv * OCAPS * OLEN;      // 65536
    caps_kernel<<<dim3(nblocks), dim3(T), 0, stream>>>(x, w, out, probs_base);
}